// Round 8
// baseline (181.000 us; speedup 1.0000x reference)
//
#include <hip/hip_runtime.h>
#include <hip/hip_bf16.h>

// MultiHeadAttention B=4,S=4096,D=64,H=4,HD=16 on gfx950.
// softmax over QUERY axis => w[s,t] = E[s,t]/colsum[t], attended = E @ (V/colsum).
// Two MFMA passes recompute E (raw v_exp_f32).  Scores via 32x32x16 bf16 MFMA
// (K=16=HD exact).  PV consumes E directly as the B-operand; the implied k->t
// permutation is absorbed by pre-permuting v' in GLOBAL memory.
// R17: k_attn 2-deep pipeline (T15): PV delayed one iter -- state {ef, af}
// in registers crosses the chunk barrier; each iter issues {score(i+1),
// PV(i-1)} as a pure-MFMA setprio cluster BEFORE the 16-exp grind, so the
// serial chain is just the exp block.  K back to global->reg 4-slot rolling
// prefetch (no chunk-top LDS kf stall; LDS 16.4KB).  Counted vmcnt(8) at the
// chunk top drains ONLY the 2 V-DMAs (kf loads stay in flight across the
// barrier).  Same accumulation order -> bitwise-identical output.

#define BB 4
#define SS 4096
#define DD 64
#define HH 4
#define HDD 16

typedef unsigned int u32;
typedef unsigned short u16;
typedef __attribute__((ext_vector_type(8))) short bfrag;     // 8 bf16
typedef __attribute__((ext_vector_type(4))) float floatx4;
typedef __attribute__((ext_vector_type(16))) float floatx16;
typedef __attribute__((ext_vector_type(2))) u32 u32x2;
typedef __attribute__((ext_vector_type(4))) u32 u32x4;

#define LOG2E 1.4426950408889634074f
#define QSCALE (LOG2E * 0.25f)

__device__ __forceinline__ float fexp2(float x) {   // raw v_exp_f32
#if __has_builtin(__builtin_amdgcn_exp2f)
  return __builtin_amdgcn_exp2f(x);
#else
  float r; asm("v_exp_f32 %0, %1" : "=v"(r) : "v"(x)); return r;
#endif
}
__device__ __forceinline__ float frcp(float x) {    // raw v_rcp_f32
#if __has_builtin(__builtin_amdgcn_rcpf)
  return __builtin_amdgcn_rcpf(x);
#else
  float r; asm("v_rcp_f32 %0, %1" : "=v"(r) : "v"(x)); return r;
#endif
}

__device__ __forceinline__ u16 f2bf(float f) {      // RNE
  u32 u = __builtin_bit_cast(u32, f);
  return (u16)((u + 0x7FFFu + ((u >> 16) & 1u)) >> 16);
}
// pack two fp32 -> bf16x2 by truncation (E>=0), single v_perm_b32
__device__ __forceinline__ u32 pack_bf(float lo, float hi) {
#if __has_builtin(__builtin_amdgcn_perm)
  return __builtin_amdgcn_perm(__builtin_bit_cast(u32, hi),
                               __builtin_bit_cast(u32, lo), 0x07060302u);
#else
  u32 a = __builtin_bit_cast(u32, lo);
  u32 b = __builtin_bit_cast(u32, hi);
  return (a >> 16) | (b & 0xFFFF0000u);
#endif
}

// global -> LDS DMA, 16B per lane.  LDS dest = wave-uniform base + lane*16.
__device__ __forceinline__ void gload_lds16(const u16* g, u16* l) {
  __builtin_amdgcn_global_load_lds(
      (const __attribute__((address_space(1))) void*)(g),
      (__attribute__((address_space(3))) void*)(l), 16, 0, 0);
}

// fragment column c (0..255 within a 256-t chunk) -> t within chunk.
__device__ __forceinline__ int tmap(int c) {
  int c5 = c & 31;
  return (c & ~31) + (c5 & 3) + ((c5 >> 2) & 1) * 8 + ((c5 >> 3) & 1) * 16
       + ((c5 >> 4) & 1) * 4;
}

// ---------------------------------------------------------------------------
// K1: projections. x[B,S,64] -> q bf16 (scaled, bias folded) [B,H,S,16];
// k bf16 FRAGMENT-LINEAR kfl[bh][t/32][lane=(e>>3)*32+(t&31)][j=e&7];
// v fp32 [B,H,S,16].
// ---------------------------------------------------------------------------
__global__ __launch_bounds__(256) void k_proj(
    const float* __restrict__ x,
    const float* __restrict__ Wq, const float* __restrict__ bq,
    const float* __restrict__ Wk, const float* __restrict__ bk,
    const float* __restrict__ Wv, const float* __restrict__ bv,
    u16* __restrict__ qb, u16* __restrict__ kfl, float* __restrict__ vf)
{
  __shared__ float xs[16 * 64];
  const int tid = threadIdx.x;
  const int blk = blockIdx.x;            // B*S/16 = 1024
  const int b   = blk >> 8;
  const int s0  = (blk & 255) << 4;
  ((float4*)xs)[tid] = ((const float4*)(x + ((size_t)b * SS + s0) * DD))[tid];
  __syncthreads();

  const int col = tid & 63, h = col >> 4, e = col & 15;
  const int rg  = tid >> 6;              // wave id; 4 rows each
  float aq[4] = {0,0,0,0}, ak[4] = {0,0,0,0}, av[4] = {0,0,0,0};
  const int wofs = h * (DD * HDD) + e;
#pragma unroll 4
  for (int d = 0; d < DD; ++d) {
    float wq = Wq[wofs + d * HDD];
    float wk = Wk[wofs + d * HDD];
    float wv = Wv[wofs + d * HDD];
    const float* xr = xs + (rg * 4) * 64 + d;
#pragma unroll
    for (int r = 0; r < 4; ++r) {
      float xv = xr[r * 64];
      aq[r] += xv * wq; ak[r] += xv * wk; av[r] += xv * wv;
    }
  }
  const float bqv = bq[col], bkv = bk[col], bvv = bv[col];
  const int bh = b * HH + h;
  size_t base = ((size_t)bh * SS + (s0 + rg * 4)) * HDD + e;
#pragma unroll
  for (int r = 0; r < 4; ++r) {
    int t = s0 + rg * 4 + r;
    qb[base + r * HDD] = f2bf((aq[r] + bqv) * QSCALE);
    vf[base + r * HDD] = av[r] + bvv;
    size_t kidx = (((size_t)bh * 128 + (t >> 5)) * 64
                 + (e >> 3) * 32 + (t & 31)) * 8 + (e & 7);
    kfl[kidx] = f2bf(ak[r] + bkv);
  }
}

// ---------------------------------------------------------------------------
// K2: fused colsum + v'-prep, 512-thr blocks.  Wave w: t-sub = w&3 (32 t),
// s-half = w>>2 (2048 s = 64 MFMAs).  Score-MFMA ping-pong with 4 rotating
// NAMED q regs; kf reads fragment-linear kfl.  Pack phase (threads 0..255)
// emits the swizzled/packed v' half-chunk: vp[bh][chunk256][flat4096],
// flat = e*256 + (cc^(e&7))*8 + j, c = cc*8+j, t = tmap(c).
// ---------------------------------------------------------------------------
__global__ __launch_bounds__(512, 4) void k_csvp(
    const u16* __restrict__ qb, const u16* __restrict__ kfl,
    const float* __restrict__ vf, u16* __restrict__ vp)
{
  __shared__ float vstage[128 * 16];     // [tl][e], 8 KB
  __shared__ float cpart[2][128];
  __shared__ float rcl[128];
  const int tid = threadIdx.x;
  const int lane = tid & 63, w = tid >> 6;
  const int l31 = lane & 31, hl = lane >> 5;
  const int bx = blockIdx.x;             // 32 t-blocks of 128
  const int bh = blockIdx.y;             // 16
  const int shalf = w >> 2;
  const size_t base = (size_t)bh * (SS * HDD);

  // stage the block's v tile (independent of the colsum stream)
  {
    const float4* vsrc4 = (const float4*)(vf + ((size_t)bh * SS + bx * 128) * HDD);
    ((float4*)vstage)[tid] = vsrc4[tid];
  }

  const int g = bx * 4 + (w & 3);
  const bfrag kf = *(const bfrag*)(kfl + (((size_t)bh * 128 + g) * 64 + lane) * 8);
  const u16* qpc = qb + base + ((size_t)shalf * 2048 + l31) * HDD + hl * 8;
  const floatx16 z16 = {0.f};
  float c0 = 0.f, c1 = 0.f, c2 = 0.f, c3 = 0.f;

#define LQ(i) (*(const bfrag*)(qpc + (size_t)(i) * (32 * HDD)))
#define ACCUM(dv)                                   \
  do {                                              \
    _Pragma("unroll")                               \
    for (int j = 0; j < 4; ++j) {                   \
      c0 += fexp2((dv)[4 * j + 0]);                 \
      c1 += fexp2((dv)[4 * j + 1]);                 \
      c2 += fexp2((dv)[4 * j + 2]);                 \
      c3 += fexp2((dv)[4 * j + 3]);                 \
    }                                               \
  } while (0)
#define STEP(qr, ri)                                                        \
  do {                                                                      \
    floatx16 dB = __builtin_amdgcn_mfma_f32_32x32x16_bf16(qr, kf, z16, 0, 0, 0); \
    qr = LQ(ri);                                                            \
    ACCUM(dA);                                                              \
    dA = dB;                                                                \
  } while (0)

  bfrag q0 = LQ(0), q1 = LQ(1), q2v = LQ(2), q3 = LQ(3);
  floatx16 dA = __builtin_amdgcn_mfma_f32_32x32x16_bf16(q0, kf, z16, 0, 0, 0);
  q0 = LQ(4);
#pragma unroll 1
  for (int o = 0; o < 2; ++o) {          // rolled: I-cache
#pragma unroll
    for (int i = 0; i < 32; i += 4) {
      STEP(q1,  i + 5);
      STEP(q2v, i + 6);
      STEP(q3,  i + 7);
      STEP(q0,  i + 8);
    }
    qpc += 32 * 32 * HDD;
  }
#undef STEP
#undef LQ
#undef ACCUM

  float c = (c0 + c1) + (c2 + c3);
  c += __shfl_xor(c, 32, 64);
  if (hl == 0)
    cpart[shalf][(w & 3) * 32 + l31] = c;
  __syncthreads();
  if (tid < 128)
    rcl[tid] = frcp(cpart[0][tid] + cpart[1][tid]);
  __syncthreads();

  // pack phase: threads 0..255 -> (e, poff); block owns half-chunk h0 = bx&1.
  if (tid < 256) {
    const int e = tid >> 4;                          // 0..15
    const int h0 = bx & 1;
    const int poff = h0 * 16 + (tid & 15);           // write cc-position
    const int cc = poff ^ (e & 7);                   // source column block
    const int h128 = h0 * 128;
    u32 r[4];
#pragma unroll
    for (int jj = 0; jj < 4; ++jj) {
      int ta = tmap(cc * 8 + 2 * jj)     - h128;     // local t within 128
      int tb = tmap(cc * 8 + 2 * jj + 1) - h128;
      u16 lo = f2bf(vstage[ta * 16 + e] * rcl[ta]);
      u16 hi = f2bf(vstage[tb * 16 + e] * rcl[tb]);
      r[jj] = (u32)lo | ((u32)hi << 16);
    }
    u16* outb = vp + ((size_t)bh * 16 + (bx >> 1)) * 4096;
    u32x4 vv = {r[0], r[1], r[2], r[3]};
    *(u32x4*)(outb + e * 256 + poff * 8) = vv;
  }
}

// ---------------------------------------------------------------------------
// K3: attended partials = E @ v' over a 2048-t half: eight 256-t chunks.
// 2-deep pipeline: PV delayed one iter (state ef/af in REGISTERS crosses the
// chunk barrier); per iter the wave issues {score(i+1), PV(i-1)} as a
// setprio'd pure-MFMA cluster, then refills one kf slot (global->reg,
// consumed 3-4 iters later), then grinds 16 exps + 8 packs.  V chunks DMA
// into double-buffered LDS; counted vmcnt(8) at the chunk top drains only
// the 2 V-DMAs (kf loads remain in flight across the barrier).
// LDS 16.4 KB; grid 1024 = 4 blocks/CU; lb(256,4).
// ---------------------------------------------------------------------------
__global__ __launch_bounds__(256, 4) void k_attn(
    const u16* __restrict__ qb, const u16* __restrict__ kfl,
    const u16* __restrict__ vp, float* __restrict__ attp)
{
  __shared__ __align__(16) u16 vls[2][4096];       // 2 x 8 KB
  const int tid  = threadIdx.x;
  const int lane = tid & 63, w = tid >> 6;
  const int l31 = lane & 31, hl = lane >> 5;
  const int bh = blockIdx.z, b = bh >> 2, h = bh & 3;
  const int tph = blockIdx.y;                      // 0..1 (t-half)
  const int s0 = blockIdx.x * 128 + w * 32;
  const size_t base = (size_t)bh * (SS * HDD);

  const bfrag qf = *(const bfrag*)(qb + base + (size_t)(s0 + l31) * HDD + hl * 8);
  const floatx16 z16 = {0.f};
  floatx16 acc0 = {0.f}, acc1 = {0.f};

  const u16* vsrc = vp  + ((size_t)bh * 16  + tph * 8)  * 4096;
  const u16* ksrc = kfl + ((size_t)bh * 128 + tph * 64) * 512;   // 8 grp/chunk
  const int eb = l31 & 7;

#define STAGE(ch, buf)                                                \
  do {                                                                \
    const u16* gv = vsrc + (ch) * 4096 + w * 1024 + lane * 8;         \
    u16* lv = &vls[buf][0] + w * 1024;                                \
    gload_lds16(gv, lv);                                              \
    gload_lds16(gv + 512, lv + 512);                                  \
  } while (0)

  STAGE(0, 0);                           // 2 DMA (oldest in vmcnt order)
  bfrag kfr[4];                          // 4-slot rotation, static indices
#pragma unroll
  for (int g = 0; g < 4; ++g)
    kfr[g] = *(const bfrag*)(ksrc + (size_t)g * 512 + lane * 8);
  // auto-wait here (vmcnt<=3) also drains the 2 older DMAs before ch0's reads
  floatx16 dA = __builtin_amdgcn_mfma_f32_32x32x16_bf16(kfr[0], qf, z16, 0, 0, 0);

  // pipeline state (registers; survives chunk barriers)
  u32x4 efL = {0,0,0,0}, efH = {0,0,0,0};
  u32x4 afA0 = {0,0,0,0}, afA1 = {0,0,0,0};
  u32x4 pf0, pf1;

#pragma unroll 1
  for (int ch = 0; ch < 8; ++ch) {
    // 2 V-DMAs for this chunk are the 2 oldest of <=10 outstanding -> counted
    // wait is ~free; kf loads stay in flight across the barrier.
    asm volatile("s_waitcnt vmcnt(8)" ::: "memory");
    __builtin_amdgcn_s_barrier();
    __builtin_amdgcn_sched_barrier(0);
    if (ch < 7) STAGE(ch + 1, (ch + 1) & 1);

    const u16* vrow = &vls[ch & 1][0] + (l31 & 15) * 256;
    {
      const int cc = hl * 2;
      pf0 = *(const u32x4*)(vrow + ((cc ^ eb) << 3));
      pf1 = *(const u32x4*)(vrow + (((cc + 1) ^ eb) << 3));
    }

#pragma unroll
    for (int it = 0; it < 8; ++it) {
      __builtin_amdgcn_s_setprio(1);
      // score(ch, it+1) -- or score(ch+1, 0) at it==7 (kfr[0] refilled at it=0;
      // at ch==7 this is a dead recompute, consumed by nothing)
      floatx16 dB;
      if (it < 7)
        dB = __builtin_amdgcn_mfma_f32_32x32x16_bf16(kfr[(it + 1) & 3], qf, z16, 0, 0, 0);
      else
        dB = __builtin_amdgcn_mfma_f32_32x32x16_bf16(kfr[0], qf, z16, 0, 0, 0);
      // PV of previous iteration (registers; skip the very first)
      if (it > 0 || ch > 0) {
        acc0 = __builtin_amdgcn_mfma_f32_32x32x16_bf16(
            __builtin_bit_cast(bfrag, afA0), __builtin_bit_cast(bfrag, efL), acc0, 0, 0, 0);
        acc1 = __builtin_amdgcn_mfma_f32_32x32x16_bf16(
            __builtin_bit_cast(bfrag, afA1), __builtin_bit_cast(bfrag, efH), acc1, 0, 0, 0);
      }
      __builtin_amdgcn_s_setprio(0);

      // kf slot refill: its 0..3 load (ch, it+4); its 4..7 load (ch+1, it-4)
      if (it < 4)
        kfr[it & 3] = *(const bfrag*)(ksrc + (size_t)(ch * 4096 + (it + 4) * 512) + lane * 8);
      else if (ch < 7)
        kfr[it & 3] = *(const bfrag*)(ksrc + (size_t)((ch + 1) * 4096 + (it - 4) * 512) + lane * 8);

      // rotate af state, then prefetch next iteration's v-rows
      afA0 = pf0; afA1 = pf1;
      if (it < 7) {
        const int cc = (it + 1) * 4 + hl * 2;
        pf0 = *(const u32x4*)(vrow + ((cc ^ eb) << 3));
        pf1 = *(const u32x4*)(vrow + (((cc + 1) ^ eb) << 3));
      }

      // exp/pack current score -> new ef state
      u32 w0 = pack_bf(fexp2(dA[0]),  fexp2(dA[1]));
      u32 w1 = pack_bf(fexp2(dA[2]),  fexp2(dA[3]));
      u32 w2 = pack_bf(fexp2(dA[4]),  fexp2(dA[5]));
      u32 w3 = pack_bf(fexp2(dA[6]),  fexp2(dA[7]));
      u32 w4 = pack_bf(fexp2(dA[8]),  fexp2(dA[9]));
      u32 w5 = pack_bf(fexp2(dA[10]), fexp2(dA[11]));
      u32 w6 = pack_bf(fexp2(dA[12]), fexp2(dA[13]));
      u32 w7 = pack_bf(fexp2(dA[14]), fexp2(dA[15]));
      efL = (u32x4){w0, w1, w2, w3};
      efH = (u32x4){w4, w5, w6, w7};
      dA = dB;
    }
  }
#undef STAGE

  // epilogue: PV of the final iteration (7,7)
  acc0 = __builtin_amdgcn_mfma_f32_32x32x16_bf16(
      __builtin_bit_cast(bfrag, afA0), __builtin_bit_cast(bfrag, efL), acc0, 0, 0, 0);
  acc1 = __builtin_amdgcn_mfma_f32_32x32x16_bf16(
      __builtin_bit_cast(bfrag, afA1), __builtin_bit_cast(bfrag, efH), acc1, 0, 0, 0);

  floatx16 acc = acc0 + acc1;
  // D[e][s]: col=l31 -> s; rows r=0..3 -> e=4hl+r, r=4..7 -> e=8+4hl+(r-4)
  float* ao = attp + (((size_t)tph * BB + b) * SS + s0 + l31) * (HH * HDD)
            + h * HDD + 4 * hl;
  float4 lo4 = {acc[0], acc[1], acc[2], acc[3]};
  float4 hi4 = {acc[4], acc[5], acc[6], acc[7]};
  *(float4*)ao       = lo4;
  *(float4*)(ao + 8) = hi4;
}

// ---------------------------------------------------------------------------
// K4: out_pre = (sum of 2 attended partials) @ Wo + bo, fused partial expsum
// over each block's 8 rows -> part[b][512][64].  Wo AND the block's 8x128
// att tile staged in LDS.  Same summation order as before.
// ---------------------------------------------------------------------------
__global__ __launch_bounds__(256) void k_oproj(
    const float* __restrict__ att, const float* __restrict__ Wo,
    const float* __restrict__ bo, float* __restrict__ outp,
    float* __restrict__ part)
{
  __shared__ float wols[64 * 64];
  __shared__ float atts[8][128];         // [row][half*64 + c]
  __shared__ float red[4][64];
  const int tid = threadIdx.x;
  const int blk = blockIdx.x;            // 2048
  const int b = blk >> 9, s0 = (blk & 511) << 3;
#pragma unroll
  for (int i = 0; i < 4; ++i)
    ((float4*)wols)[tid + 256 * i] = ((const float4*)Wo)[tid + 256 * i];
  // stage att tile: r = tid>>5, q = tid&31 -> half = q>>4, j4 = (q&15)*4
  {
    const int r = tid >> 5, q = tid & 31;
    const int half = q >> 4, j4 = (q & 15) << 2;
    const float4 v = *(const float4*)(
        att + (((size_t)half * BB + b) * SS + s0 + r) * 64 + j4);
    *(float4*)(&atts[r][half * 64 + j4]) = v;
  }
  __syncthreads();

  const int d = tid & 63, sg = tid >> 6;
  const float bov = bo[d];
  float es = 0.f;
#pragma unroll
  for (int r = 0; r < 2; ++r) {
    const int row = sg * 2 + r;
    float acc = bov;
#pragma unroll
    for (int c = 0; c < 64; ++c)
      acc += (atts[row][c] + atts[row][64 + c]) * wols[c * 64 + d];
    outp[((size_t)b * SS + s0 + row) * 64 + d] = acc;
    es += fexp2(acc * LOG2E);
  }
  red[sg][d] = es;
  __syncthreads();
  if (tid < 64)
    part[((size_t)b * 512 + (blk & 511)) * 64 + tid] =
        red[0][tid] + red[1][tid] + red[2][tid] + red[3][tid];
}

// ---------------------------------------------------------------------------
// K5: out = exp(out_pre) * rcp(sum_s exp(out_pre))  (512 partials per (b,d))
// ---------------------------------------------------------------------------
__global__ __launch_bounds__(256) void k_softmax(
    const float* __restrict__ outp, const float* __restrict__ part,
    float* __restrict__ out)
{
  __shared__ float red[4][64];
  __shared__ float rs[64];
  const int tid = threadIdx.x, d = tid & 63, sg = tid >> 6;
  const int st = blockIdx.x;             // 64 s-tiles of 64
  const int b = blockIdx.y;
  {
    float e = 0.f;
    const float* pp = part + ((size_t)b * 512 + sg * 128) * 64 + d;
#pragma unroll 8
    for (int c = 0; c < 128; ++c) e += pp[c * 64];
    red[sg][d] = e;
  }
  __syncthreads();
  if (tid < 64)
    rs[tid] = frcp(red[0][tid] + red[1][tid] + red[2][tid] + red[3][tid]);
  __syncthreads();
  const float r = rs[d];
  const size_t rowbase = ((size_t)b * SS + st * 64 + sg * 16) * 64 + d;
#pragma unroll 4
  for (int i = 0; i < 16; ++i)
    out[rowbase + i * 64] = fexp2(outp[rowbase + i * 64] * LOG2E) * r;
}

// ---------------------------------------------------------------------------
extern "C" void kernel_launch(void* const* d_in, const int* in_sizes, int n_in,
                              void* d_out, int out_size, void* d_ws, size_t ws_size,
                              hipStream_t stream) {
  const float* x  = (const float*)d_in[0];
  const float* Wq = (const float*)d_in[1];
  const float* bq = (const float*)d_in[2];
  const float* Wk = (const float*)d_in[3];
  const float* bk = (const float*)d_in[4];
  const float* Wv = (const float*)d_in[5];
  const float* bv = (const float*)d_in[6];
  const float* Wo = (const float*)d_in[7];
  const float* bo = (const float*)d_in[8];

  char* ws = (char*)d_ws;
  constexpr size_t QB_OFF  = 0;                    // 2 MiB u16
  constexpr size_t KF_OFF  = (size_t)2  << 20;     // 2 MiB u16 (fragment-linear K)
  constexpr size_t VF_OFF  = (size_t)4  << 20;     // 4 MiB f32
  constexpr size_t VP_OFF  = (size_t)8  << 20;     // 2 MiB u16 (v' fragments)
  constexpr size_t ATT_OFF = (size_t)10 << 20;     // 8 MiB f32 (2 partials)
  constexpr size_t OUT_OFF = (size_t)18 << 20;     // 4 MiB f32
  constexpr size_t PT_OFF  = (size_t)22 << 20;     // 512 KiB f32

  u16*   qb   = (u16*)  (ws + QB_OFF);
  u16*   kfl  = (u16*)  (ws + KF_OFF);
  float* vf   = (float*)(ws + VF_OFF);
  u16*   vpb  = (u16*)  (ws + VP_OFF);
  float* attp = (float*)(ws + ATT_OFF);
  float* outp = (float*)(ws + OUT_OFF);
  float* part = (float*)(ws + PT_OFF);
  float* out  = (float*)d_out;

  hipLaunchKernelGGL(k_proj,    dim3(1024),       dim3(256), 0, stream,
                     x, Wq, bq, Wk, bk, Wv, bv, qb, kfl, vf);
  hipLaunchKernelGGL(k_csvp,    dim3(32, 16),     dim3(512), 0, stream,
                     qb, kfl, vf, vpb);
  hipLaunchKernelGGL(k_attn,    dim3(32, 2, 16),  dim3(256), 0, stream,
                     qb, kfl, vpb, attp);
  hipLaunchKernelGGL(k_oproj,   dim3(2048),       dim3(256), 0, stream,
                     attp, Wo, bo, outp, part);
  hipLaunchKernelGGL(k_softmax, dim3(64, 4),      dim3(256), 0, stream, outp, part, out);
}

// Round 9
// 173.100 us; speedup vs baseline: 1.0456x; 1.0456x over previous
//
#include <hip/hip_runtime.h>
#include <hip/hip_bf16.h>

// MultiHeadAttention B=4,S=4096,D=64,H=4,HD=16 on gfx950.
// softmax over QUERY axis => w[s,t] = E[s,t]/colsum[t], attended = E @ (V/colsum).
// Two MFMA passes recompute E (raw v_exp_f32).  Scores via 32x32x16 bf16 MFMA
// (K=16=HD exact).  PV consumes E directly as the B-operand; the implied k->t
// permutation is absorbed by pre-permuting v' in GLOBAL memory.
// R18: R17's deep pipeline SPILLED (WRITE_SIZE 23.5MB vs 8.4 ideal; rolled
// ch loop + 130-reg live set under a 64-VGPR allocation).  Keep the 2-deep
// PV pipeline, shrink state: K back in LDS (kls dbuf, DMA'd with V; kf is a
// single 4-reg rotating kc slot fed by conflict-free ds_read_b128), single
// af set (loaded at iter i after PV(i-1), used at i+1), ch loop FULLY
// unrolled (static indices).  vmcnt(0)+raw s_barrier at chunk top is ~free
// (DMAs issued one full chunk earlier).  Same accumulation order -> bitwise
// identical.  Everything else unchanged from R16/R17.

#define BB 4
#define SS 4096
#define DD 64
#define HH 4
#define HDD 16

typedef unsigned int u32;
typedef unsigned short u16;
typedef __attribute__((ext_vector_type(8))) short bfrag;     // 8 bf16
typedef __attribute__((ext_vector_type(4))) float floatx4;
typedef __attribute__((ext_vector_type(16))) float floatx16;
typedef __attribute__((ext_vector_type(2))) u32 u32x2;
typedef __attribute__((ext_vector_type(4))) u32 u32x4;

#define LOG2E 1.4426950408889634074f
#define QSCALE (LOG2E * 0.25f)

__device__ __forceinline__ float fexp2(float x) {   // raw v_exp_f32
#if __has_builtin(__builtin_amdgcn_exp2f)
  return __builtin_amdgcn_exp2f(x);
#else
  float r; asm("v_exp_f32 %0, %1" : "=v"(r) : "v"(x)); return r;
#endif
}
__device__ __forceinline__ float frcp(float x) {    // raw v_rcp_f32
#if __has_builtin(__builtin_amdgcn_rcpf)
  return __builtin_amdgcn_rcpf(x);
#else
  float r; asm("v_rcp_f32 %0, %1" : "=v"(r) : "v"(x)); return r;
#endif
}

__device__ __forceinline__ u16 f2bf(float f) {      // RNE
  u32 u = __builtin_bit_cast(u32, f);
  return (u16)((u + 0x7FFFu + ((u >> 16) & 1u)) >> 16);
}
// pack two fp32 -> bf16x2 by truncation (E>=0), single v_perm_b32
__device__ __forceinline__ u32 pack_bf(float lo, float hi) {
#if __has_builtin(__builtin_amdgcn_perm)
  return __builtin_amdgcn_perm(__builtin_bit_cast(u32, hi),
                               __builtin_bit_cast(u32, lo), 0x07060302u);
#else
  u32 a = __builtin_bit_cast(u32, lo);
  u32 b = __builtin_bit_cast(u32, hi);
  return (a >> 16) | (b & 0xFFFF0000u);
#endif
}

// global -> LDS DMA, 16B per lane.  LDS dest = wave-uniform base + lane*16.
__device__ __forceinline__ void gload_lds16(const u16* g, u16* l) {
  __builtin_amdgcn_global_load_lds(
      (const __attribute__((address_space(1))) void*)(g),
      (__attribute__((address_space(3))) void*)(l), 16, 0, 0);
}

// fragment column c (0..255 within a 256-t chunk) -> t within chunk.
__device__ __forceinline__ int tmap(int c) {
  int c5 = c & 31;
  return (c & ~31) + (c5 & 3) + ((c5 >> 2) & 1) * 8 + ((c5 >> 3) & 1) * 16
       + ((c5 >> 4) & 1) * 4;
}

// ---------------------------------------------------------------------------
// K1: projections. x[B,S,64] -> q bf16 (scaled, bias folded) [B,H,S,16];
// k bf16 FRAGMENT-LINEAR kfl[bh][t/32][lane=(e>>3)*32+(t&31)][j=e&7];
// v fp32 [B,H,S,16].
// ---------------------------------------------------------------------------
__global__ __launch_bounds__(256) void k_proj(
    const float* __restrict__ x,
    const float* __restrict__ Wq, const float* __restrict__ bq,
    const float* __restrict__ Wk, const float* __restrict__ bk,
    const float* __restrict__ Wv, const float* __restrict__ bv,
    u16* __restrict__ qb, u16* __restrict__ kfl, float* __restrict__ vf)
{
  __shared__ float xs[16 * 64];
  const int tid = threadIdx.x;
  const int blk = blockIdx.x;            // B*S/16 = 1024
  const int b   = blk >> 8;
  const int s0  = (blk & 255) << 4;
  ((float4*)xs)[tid] = ((const float4*)(x + ((size_t)b * SS + s0) * DD))[tid];
  __syncthreads();

  const int col = tid & 63, h = col >> 4, e = col & 15;
  const int rg  = tid >> 6;              // wave id; 4 rows each
  float aq[4] = {0,0,0,0}, ak[4] = {0,0,0,0}, av[4] = {0,0,0,0};
  const int wofs = h * (DD * HDD) + e;
#pragma unroll 4
  for (int d = 0; d < DD; ++d) {
    float wq = Wq[wofs + d * HDD];
    float wk = Wk[wofs + d * HDD];
    float wv = Wv[wofs + d * HDD];
    const float* xr = xs + (rg * 4) * 64 + d;
#pragma unroll
    for (int r = 0; r < 4; ++r) {
      float xv = xr[r * 64];
      aq[r] += xv * wq; ak[r] += xv * wk; av[r] += xv * wv;
    }
  }
  const float bqv = bq[col], bkv = bk[col], bvv = bv[col];
  const int bh = b * HH + h;
  size_t base = ((size_t)bh * SS + (s0 + rg * 4)) * HDD + e;
#pragma unroll
  for (int r = 0; r < 4; ++r) {
    int t = s0 + rg * 4 + r;
    qb[base + r * HDD] = f2bf((aq[r] + bqv) * QSCALE);
    vf[base + r * HDD] = av[r] + bvv;
    size_t kidx = (((size_t)bh * 128 + (t >> 5)) * 64
                 + (e >> 3) * 32 + (t & 31)) * 8 + (e & 7);
    kfl[kidx] = f2bf(ak[r] + bkv);
  }
}

// ---------------------------------------------------------------------------
// K2: fused colsum + v'-prep, 512-thr blocks.  Wave w: t-sub = w&3 (32 t),
// s-half = w>>2 (2048 s = 64 MFMAs).  Score-MFMA ping-pong with 4 rotating
// NAMED q regs; kf reads fragment-linear kfl.  Pack phase (threads 0..255)
// emits the swizzled/packed v' half-chunk: vp[bh][chunk256][flat4096],
// flat = e*256 + (cc^(e&7))*8 + j, c = cc*8+j, t = tmap(c).
// ---------------------------------------------------------------------------
__global__ __launch_bounds__(512, 4) void k_csvp(
    const u16* __restrict__ qb, const u16* __restrict__ kfl,
    const float* __restrict__ vf, u16* __restrict__ vp)
{
  __shared__ float vstage[128 * 16];     // [tl][e], 8 KB
  __shared__ float cpart[2][128];
  __shared__ float rcl[128];
  const int tid = threadIdx.x;
  const int lane = tid & 63, w = tid >> 6;
  const int l31 = lane & 31, hl = lane >> 5;
  const int bx = blockIdx.x;             // 32 t-blocks of 128
  const int bh = blockIdx.y;             // 16
  const int shalf = w >> 2;
  const size_t base = (size_t)bh * (SS * HDD);

  // stage the block's v tile (independent of the colsum stream)
  {
    const float4* vsrc4 = (const float4*)(vf + ((size_t)bh * SS + bx * 128) * HDD);
    ((float4*)vstage)[tid] = vsrc4[tid];
  }

  const int g = bx * 4 + (w & 3);
  const bfrag kf = *(const bfrag*)(kfl + (((size_t)bh * 128 + g) * 64 + lane) * 8);
  const u16* qpc = qb + base + ((size_t)shalf * 2048 + l31) * HDD + hl * 8;
  const floatx16 z16 = {0.f};
  float c0 = 0.f, c1 = 0.f, c2 = 0.f, c3 = 0.f;

#define LQ(i) (*(const bfrag*)(qpc + (size_t)(i) * (32 * HDD)))
#define ACCUM(dv)                                   \
  do {                                              \
    _Pragma("unroll")                               \
    for (int j = 0; j < 4; ++j) {                   \
      c0 += fexp2((dv)[4 * j + 0]);                 \
      c1 += fexp2((dv)[4 * j + 1]);                 \
      c2 += fexp2((dv)[4 * j + 2]);                 \
      c3 += fexp2((dv)[4 * j + 3]);                 \
    }                                               \
  } while (0)
#define STEP(qr, ri)                                                        \
  do {                                                                      \
    floatx16 dB = __builtin_amdgcn_mfma_f32_32x32x16_bf16(qr, kf, z16, 0, 0, 0); \
    qr = LQ(ri);                                                            \
    ACCUM(dA);                                                              \
    dA = dB;                                                                \
  } while (0)

  bfrag q0 = LQ(0), q1 = LQ(1), q2v = LQ(2), q3 = LQ(3);
  floatx16 dA = __builtin_amdgcn_mfma_f32_32x32x16_bf16(q0, kf, z16, 0, 0, 0);
  q0 = LQ(4);
#pragma unroll 1
  for (int o = 0; o < 2; ++o) {          // rolled: I-cache
#pragma unroll
    for (int i = 0; i < 32; i += 4) {
      STEP(q1,  i + 5);
      STEP(q2v, i + 6);
      STEP(q3,  i + 7);
      STEP(q0,  i + 8);
    }
    qpc += 32 * 32 * HDD;
  }
#undef STEP
#undef LQ
#undef ACCUM

  float c = (c0 + c1) + (c2 + c3);
  c += __shfl_xor(c, 32, 64);
  if (hl == 0)
    cpart[shalf][(w & 3) * 32 + l31] = c;
  __syncthreads();
  if (tid < 128)
    rcl[tid] = frcp(cpart[0][tid] + cpart[1][tid]);
  __syncthreads();

  // pack phase: threads 0..255 -> (e, poff); block owns half-chunk h0 = bx&1.
  if (tid < 256) {
    const int e = tid >> 4;                          // 0..15
    const int h0 = bx & 1;
    const int poff = h0 * 16 + (tid & 15);           // write cc-position
    const int cc = poff ^ (e & 7);                   // source column block
    const int h128 = h0 * 128;
    u32 r[4];
#pragma unroll
    for (int jj = 0; jj < 4; ++jj) {
      int ta = tmap(cc * 8 + 2 * jj)     - h128;     // local t within 128
      int tb = tmap(cc * 8 + 2 * jj + 1) - h128;
      u16 lo = f2bf(vstage[ta * 16 + e] * rcl[ta]);
      u16 hi = f2bf(vstage[tb * 16 + e] * rcl[tb]);
      r[jj] = (u32)lo | ((u32)hi << 16);
    }
    u16* outb = vp + ((size_t)bh * 16 + (bx >> 1)) * 4096;
    u32x4 vv = {r[0], r[1], r[2], r[3]};
    *(u32x4*)(outb + e * 256 + poff * 8) = vv;
  }
}

// ---------------------------------------------------------------------------
// K3: attended partials = E @ v' over a 2048-t half: eight 256-t chunks.
// K and v' both DMA into double-buffered LDS; inner loop is VMEM-free.
// 2-deep PV pipeline with MINIMAL state: kc (4 reg, rotating kf slot fed by
// ds_read_b128), af (8 reg, loaded at iter i after PV(i-1) consumed it),
// ef (8 reg).  Per iter: setprio{score(i+1), PV(i-1)}, load kc(i+2),
// load af(i), exp-grind dA->ef(i).  Score pipe restarts each chunk (~200cyc
// bubble); af/ef/acc cross the barrier in registers.  Chunk top:
// vmcnt(0)+raw s_barrier (~free: DMAs issued one full chunk earlier).
// LDS 32.8 KB; grid 1024 = 4 blocks/CU; lb(256,4); ch loop FULLY unrolled.
// ---------------------------------------------------------------------------
__global__ __launch_bounds__(256, 4) void k_attn(
    const u16* __restrict__ qb, const u16* __restrict__ kfl,
    const u16* __restrict__ vp, float* __restrict__ attp)
{
  __shared__ __align__(16) u16 vls[2][4096];       // 2 x 8 KB
  __shared__ __align__(16) u16 kls[2][4096];       // 2 x 8 KB
  const int tid  = threadIdx.x;
  const int lane = tid & 63, w = tid >> 6;
  const int l31 = lane & 31, hl = lane >> 5;
  const int bh = blockIdx.z, b = bh >> 2, h = bh & 3;
  const int tph = blockIdx.y;                      // 0..1 (t-half)
  const int s0 = blockIdx.x * 128 + w * 32;
  const size_t base = (size_t)bh * (SS * HDD);

  const bfrag qf = *(const bfrag*)(qb + base + (size_t)(s0 + l31) * HDD + hl * 8);
  const floatx16 z16 = {0.f};
  floatx16 acc0 = {0.f}, acc1 = {0.f};

  const u16* vsrc = vp  + ((size_t)bh * 16  + tph * 8)  * 4096;
  const u16* ksrc = kfl + ((size_t)bh * 128 + tph * 64) * 512;   // 8 grp/chunk
  const int eb = l31 & 7;

#define STAGE(ch, buf)                                                \
  do {                                                                \
    const u16* gv = vsrc + (ch) * 4096 + w * 1024 + lane * 8;         \
    u16* lv = &vls[buf][0] + w * 1024;                                \
    gload_lds16(gv, lv);                                              \
    gload_lds16(gv + 512, lv + 512);                                  \
    const u16* gk = ksrc + (ch) * 4096 + w * 1024 + lane * 8;         \
    u16* lk = &kls[buf][0] + w * 1024;                                \
    gload_lds16(gk, lk);                                              \
    gload_lds16(gk + 512, lk + 512);                                  \
  } while (0)

  STAGE(0, 0);

  // pipeline state (registers; survives chunk barriers)
  u32x4 efL = {0,0,0,0}, efH = {0,0,0,0};
  u32x4 af0 = {0,0,0,0}, af1 = {0,0,0,0};

#pragma unroll
  for (int ch = 0; ch < 8; ++ch) {
    // DMAs for this chunk were issued a full chunk ago -> ~free wait.
    asm volatile("s_waitcnt vmcnt(0)" ::: "memory");
    __builtin_amdgcn_s_barrier();
    __builtin_amdgcn_sched_barrier(0);
    if (ch < 7) STAGE(ch + 1, (ch + 1) & 1);

    const u16* vrow = &vls[ch & 1][0] + (l31 & 15) * 256;
    const u16* krow = &kls[ch & 1][0];

    // restart score pipe for this chunk
    bfrag kc = *(const bfrag*)(krow + lane * 8);
    floatx16 dA = __builtin_amdgcn_mfma_f32_32x32x16_bf16(kc, qf, z16, 0, 0, 0);
    kc = *(const bfrag*)(krow + 512 + lane * 8);

#pragma unroll
    for (int it = 0; it < 8; ++it) {
      __builtin_amdgcn_s_setprio(1);
      floatx16 dB;
      if (it < 7)     // score(ch, it+1)
        dB = __builtin_amdgcn_mfma_f32_32x32x16_bf16(kc, qf, z16, 0, 0, 0);
      if (ch > 0 || it > 0) {            // PV of previous iteration
        acc0 = __builtin_amdgcn_mfma_f32_32x32x16_bf16(
            __builtin_bit_cast(bfrag, af0), __builtin_bit_cast(bfrag, efL), acc0, 0, 0, 0);
        acc1 = __builtin_amdgcn_mfma_f32_32x32x16_bf16(
            __builtin_bit_cast(bfrag, af1), __builtin_bit_cast(bfrag, efH), acc1, 0, 0, 0);
      }
      __builtin_amdgcn_s_setprio(0);

      if (it < 6)     // kf for score issued next iteration
        kc = *(const bfrag*)(krow + (it + 2) * 512 + lane * 8);

      // v-rows for THIS iteration (consumed by PV at it+1)
      {
        const int cc = it * 4 + hl * 2;
        af0 = *(const u32x4*)(vrow + ((cc ^ eb) << 3));
        af1 = *(const u32x4*)(vrow + (((cc + 1) ^ eb) << 3));
      }

      // exp/pack current score -> new ef state
      u32 w0 = pack_bf(fexp2(dA[0]),  fexp2(dA[1]));
      u32 w1 = pack_bf(fexp2(dA[2]),  fexp2(dA[3]));
      u32 w2 = pack_bf(fexp2(dA[4]),  fexp2(dA[5]));
      u32 w3 = pack_bf(fexp2(dA[6]),  fexp2(dA[7]));
      u32 w4 = pack_bf(fexp2(dA[8]),  fexp2(dA[9]));
      u32 w5 = pack_bf(fexp2(dA[10]), fexp2(dA[11]));
      u32 w6 = pack_bf(fexp2(dA[12]), fexp2(dA[13]));
      u32 w7 = pack_bf(fexp2(dA[14]), fexp2(dA[15]));
      efL = (u32x4){w0, w1, w2, w3};
      efH = (u32x4){w4, w5, w6, w7};
      if (it < 7) dA = dB;
    }
  }
#undef STAGE

  // epilogue: PV of the final iteration (7,7)
  acc0 = __builtin_amdgcn_mfma_f32_32x32x16_bf16(
      __builtin_bit_cast(bfrag, af0), __builtin_bit_cast(bfrag, efL), acc0, 0, 0, 0);
  acc1 = __builtin_amdgcn_mfma_f32_32x32x16_bf16(
      __builtin_bit_cast(bfrag, af1), __builtin_bit_cast(bfrag, efH), acc1, 0, 0, 0);

  floatx16 acc = acc0 + acc1;
  // D[e][s]: col=l31 -> s; rows r=0..3 -> e=4hl+r, r=4..7 -> e=8+4hl+(r-4)
  float* ao = attp + (((size_t)tph * BB + b) * SS + s0 + l31) * (HH * HDD)
            + h * HDD + 4 * hl;
  float4 lo4 = {acc[0], acc[1], acc[2], acc[3]};
  float4 hi4 = {acc[4], acc[5], acc[6], acc[7]};
  *(float4*)ao       = lo4;
  *(float4*)(ao + 8) = hi4;
}

// ---------------------------------------------------------------------------
// K4: out_pre = (sum of 2 attended partials) @ Wo + bo, fused partial expsum
// over each block's 8 rows -> part[b][512][64].  Wo AND the block's 8x128
// att tile staged in LDS.  Same summation order as before.
// ---------------------------------------------------------------------------
__global__ __launch_bounds__(256) void k_oproj(
    const float* __restrict__ att, const float* __restrict__ Wo,
    const float* __restrict__ bo, float* __restrict__ outp,
    float* __restrict__ part)
{
  __shared__ float wols[64 * 64];
  __shared__ float atts[8][128];         // [row][half*64 + c]
  __shared__ float red[4][64];
  const int tid = threadIdx.x;
  const int blk = blockIdx.x;            // 2048
  const int b = blk >> 9, s0 = (blk & 511) << 3;
#pragma unroll
  for (int i = 0; i < 4; ++i)
    ((float4*)wols)[tid + 256 * i] = ((const float4*)Wo)[tid + 256 * i];
  // stage att tile: r = tid>>5, q = tid&31 -> half = q>>4, j4 = (q&15)*4
  {
    const int r = tid >> 5, q = tid & 31;
    const int half = q >> 4, j4 = (q & 15) << 2;
    const float4 v = *(const float4*)(
        att + (((size_t)half * BB + b) * SS + s0 + r) * 64 + j4);
    *(float4*)(&atts[r][half * 64 + j4]) = v;
  }
  __syncthreads();

  const int d = tid & 63, sg = tid >> 6;
  const float bov = bo[d];
  float es = 0.f;
#pragma unroll
  for (int r = 0; r < 2; ++r) {
    const int row = sg * 2 + r;
    float acc = bov;
#pragma unroll
    for (int c = 0; c < 64; ++c)
      acc += (atts[row][c] + atts[row][64 + c]) * wols[c * 64 + d];
    outp[((size_t)b * SS + s0 + row) * 64 + d] = acc;
    es += fexp2(acc * LOG2E);
  }
  red[sg][d] = es;
  __syncthreads();
  if (tid < 64)
    part[((size_t)b * 512 + (blk & 511)) * 64 + tid] =
        red[0][tid] + red[1][tid] + red[2][tid] + red[3][tid];
}

// ---------------------------------------------------------------------------
// K5: out = exp(out_pre) * rcp(sum_s exp(out_pre))  (512 partials per (b,d))
// ---------------------------------------------------------------------------
__global__ __launch_bounds__(256) void k_softmax(
    const float* __restrict__ outp, const float* __restrict__ part,
    float* __restrict__ out)
{
  __shared__ float red[4][64];
  __shared__ float rs[64];
  const int tid = threadIdx.x, d = tid & 63, sg = tid >> 6;
  const int st = blockIdx.x;             // 64 s-tiles of 64
  const int b = blockIdx.y;
  {
    float e = 0.f;
    const float* pp = part + ((size_t)b * 512 + sg * 128) * 64 + d;
#pragma unroll 8
    for (int c = 0; c < 128; ++c) e += pp[c * 64];
    red[sg][d] = e;
  }
  __syncthreads();
  if (tid < 64)
    rs[tid] = frcp(red[0][tid] + red[1][tid] + red[2][tid] + red[3][tid]);
  __syncthreads();
  const float r = rs[d];
  const size_t rowbase = ((size_t)b * SS + st * 64 + sg * 16) * 64 + d;
#pragma unroll 4
  for (int i = 0; i < 16; ++i)
    out[rowbase + i * 64] = fexp2(outp[rowbase + i * 64] * LOG2E) * r;
}

// ---------------------------------------------------------------------------
extern "C" void kernel_launch(void* const* d_in, const int* in_sizes, int n_in,
                              void* d_out, int out_size, void* d_ws, size_t ws_size,
                              hipStream_t stream) {
  const float* x  = (const float*)d_in[0];
  const float* Wq = (const float*)d_in[1];
  const float* bq = (const float*)d_in[2];
  const float* Wk = (const float*)d_in[3];
  const float* bk = (const float*)d_in[4];
  const float* Wv = (const float*)d_in[5];
  const float* bv = (const float*)d_in[6];
  const float* Wo = (const float*)d_in[7];
  const float* bo = (const float*)d_in[8];

  char* ws = (char*)d_ws;
  constexpr size_t QB_OFF  = 0;                    // 2 MiB u16
  constexpr size_t KF_OFF  = (size_t)2  << 20;     // 2 MiB u16 (fragment-linear K)
  constexpr size_t VF_OFF  = (size_t)4  << 20;     // 4 MiB f32
  constexpr size_t VP_OFF  = (size_t)8  << 20;     // 2 MiB u16 (v' fragments)
  constexpr size_t ATT_OFF = (size_t)10 << 20;     // 8 MiB f32 (2 partials)
  constexpr size_t OUT_OFF = (size_t)18 << 20;     // 4 MiB f32
  constexpr size_t PT_OFF  = (size_t)22 << 20;     // 512 KiB f32

  u16*   qb   = (u16*)  (ws + QB_OFF);
  u16*   kfl  = (u16*)  (ws + KF_OFF);
  float* vf   = (float*)(ws + VF_OFF);
  u16*   vpb  = (u16*)  (ws + VP_OFF);
  float* attp = (float*)(ws + ATT_OFF);
  float* outp = (float*)(ws + OUT_OFF);
  float* part = (float*)(ws + PT_OFF);
  float* out  = (float*)d_out;

  hipLaunchKernelGGL(k_proj,    dim3(1024),       dim3(256), 0, stream,
                     x, Wq, bq, Wk, bk, Wv, bv, qb, kfl, vf);
  hipLaunchKernelGGL(k_csvp,    dim3(32, 16),     dim3(512), 0, stream,
                     qb, kfl, vf, vpb);
  hipLaunchKernelGGL(k_attn,    dim3(32, 2, 16),  dim3(256), 0, stream,
                     qb, kfl, vpb, attp);
  hipLaunchKernelGGL(k_oproj,   dim3(2048),       dim3(256), 0, stream,
                     attp, Wo, bo, outp, part);
  hipLaunchKernelGGL(k_softmax, dim3(64, 4),      dim3(256), 0, stream, outp, part, out);
}